// Round 14
// baseline (247.872 us; speedup 1.0000x reference)
//
#include <hip/hip_runtime.h>
#include <hip/hip_bf16.h>

#define N_NODES 50000
#define N_EDGES 800000
#define C 128
#define D_IN 32
#define T0 25000
#define OUT_DIM 16
#define NBUCKETS ((N_NODES + 255) / 256)      // 196, bucket = dst>>8
#define NB1 512
#define CHUNK1 ((N_EDGES + NB1 - 1) / NB1)    // 1563
#define ENC_BLOCKS 512
#define HIST_BLOCKS 256
#define PREP_ITEMS (2 * 128 * 256 + 2 * 16 * 128)
#define PREP_BLOCKS ((PREP_ITEMS + 255) / 256)

// Pipeline: mega(encode+hist+prep) -> scanb -> bucket1 -> bucket2 ->
// gemm_fused(L0: gather+mean+GEMM -> xnew) -> gemm_fused(L1 + head -> out).
// x stored as one bf16 plane; GEMM K=256 {x*Ws_hi, mean*Wn_hi}; head
// fp32-compensated (hw hi/lo).

typedef __attribute__((ext_vector_type(8))) short short8;
typedef __attribute__((ext_vector_type(4))) float f32x4;

__device__ __forceinline__ unsigned short f2bf(float f) {
    union { float f; unsigned int i; } u; u.f = f;
    unsigned int x = u.i;
    unsigned int r = x + 0x7fffu + ((x >> 16) & 1u);
    return (unsigned short)(r >> 16);
}
__device__ __forceinline__ float bf2f(unsigned short h) {
    union { unsigned int i; float f; } u; u.i = ((unsigned int)h) << 16;
    return u.f;
}
__device__ __forceinline__ float lo_f(unsigned int w) {
    union { unsigned int i; float f; } u; u.i = w << 16;
    return u.f;
}
__device__ __forceinline__ float hi_f(unsigned int w) {
    union { unsigned int i; float f; } u; u.i = w & 0xffff0000u;
    return u.f;
}
__device__ __forceinline__ void async16(void* lds, const void* g) {
    __builtin_amdgcn_global_load_lds(
        (const __attribute__((address_space(1))) void*)g,
        (__attribute__((address_space(3))) void*)lds, 16, 0, 0);
}
__device__ __forceinline__ void add8(float* a, uint4 v) {
    a[0] += lo_f(v.x); a[1] += hi_f(v.x);
    a[2] += lo_f(v.y); a[3] += hi_f(v.y);
    a[4] += lo_f(v.z); a[5] += hi_f(v.z);
    a[6] += lo_f(v.w); a[7] += hi_f(v.w);
}

// ---------------------------------------------------------------------------
// Mega-kernel: encode (blocks 0..511, row_idx pipelined) +
// bucket hist (512..767) + weight prep (768..).
// ---------------------------------------------------------------------------
__global__ __launch_bounds__(256) void encode_hist_prep_kernel(
    const float* __restrict__ feats0, const float* __restrict__ feats1,
    const float* __restrict__ w0, const float* __restrict__ b0,
    const float* __restrict__ w1, const float* __restrict__ b1,
    const int* __restrict__ row_idx, unsigned short* __restrict__ xh,
    const int* __restrict__ dst, int* __restrict__ bucket_counts,
    const float* __restrict__ ws0, const float* __restrict__ wn0,
    const float* __restrict__ ws1, const float* __restrict__ wn1,
    const float* __restrict__ hw,
    unsigned short* __restrict__ BT0, unsigned short* __restrict__ BT1,
    unsigned short* __restrict__ hwbh, unsigned short* __restrict__ hwbl)
{
    if (blockIdx.x >= ENC_BLOCKS + HIST_BLOCKS) {
        int idx = (blockIdx.x - ENC_BLOCKS - HIST_BLOCKS) * 256 + threadIdx.x;
        const int per_layer = 128 * 256;
        if (idx < 2 * per_layer) {
            int lyr = idx / per_layer;
            int rem = idx - lyr * per_layer;
            int n = rem >> 8;
            int k = rem & 255;
            int seg = k >> 7;     // 0:Ws_hi 1:Wn_hi
            int ch = k & 127;
            const float* W = (lyr == 0) ? (seg ? wn0 : ws0)
                                        : (seg ? wn1 : ws1);
            (lyr == 0 ? BT0 : BT1)[(size_t)n * 256 + k] =
                f2bf(W[ch * 128 + n]);
            return;
        }
        int jdx = idx - 2 * per_layer;
        if (jdx >= 2 * 16 * 128) return;
        int plane = jdx >> 11;
        int rem = jdx & 2047;
        int n = rem >> 7;
        int k = rem & 127;
        float v = hw[k * OUT_DIM + n];
        unsigned short hi = f2bf(v);
        (plane ? hwbl : hwbh)[n * 136 + k] = plane ? f2bf(v - bf2f(hi)) : hi;
        return;
    }
    if (blockIdx.x >= ENC_BLOCKS) {
        __shared__ int h[NBUCKETS];
        for (int i = threadIdx.x; i < NBUCKETS; i += 256) h[i] = 0;
        __syncthreads();
        int bid = blockIdx.x - ENC_BLOCKS;
        for (int e = bid * 256 + threadIdx.x; e < N_EDGES;
             e += HIST_BLOCKS * 256)
            atomicAdd(&h[dst[e] >> 8], 1);
        __syncthreads();
        for (int i = threadIdx.x; i < NBUCKETS; i += 256)
            if (h[i]) atomicAdd(&bucket_counts[i], h[i]);
        return;
    }

    __shared__ float sw0[D_IN * C];
    __shared__ float sw1[D_IN * C];
    __shared__ float sb0[C];
    __shared__ float sb1[C];
    for (int i = threadIdx.x; i < D_IN * C; i += blockDim.x) {
        sw0[i] = w0[i];
        sw1[i] = w1[i];
    }
    if (threadIdx.x < C) {
        sb0[threadIdx.x] = b0[threadIdx.x];
        sb1[threadIdx.x] = b1[threadIdx.x];
    }
    __syncthreads();

    const int STEP = ENC_BLOCKS * 16;
    int j = threadIdx.x & 15;
    int ln = threadIdx.x >> 4;
    int n = blockIdx.x * 16 + ln;
    int r = (n < N_NODES) ? row_idx[n] : 0;
    for (; n < N_NODES; n += STEP) {
        int nn = n + STEP;
        int rn = (nn < N_NODES) ? row_idx[nn] : 0;
        const float* f = (r < T0) ? (feats0 + (size_t)r * D_IN)
                                  : (feats1 + (size_t)(r - T0) * D_IN);
        const float* W = (r < T0) ? sw0 : sw1;
        const float* B = (r < T0) ? sb0 : sb1;
        float4 f4[8];
#pragma unroll
        for (int i = 0; i < 8; ++i) f4[i] = ((const float4*)f)[i];
        float acc[8];
#pragma unroll
        for (int cc = 0; cc < 8; ++cc) acc[cc] = B[8 * j + cc];
#pragma unroll
        for (int k = 0; k < D_IN; ++k) {
            float fk = ((const float*)f4)[k];
            float4 wa = *(const float4*)&W[k * C + 8 * j];
            float4 wb = *(const float4*)&W[k * C + 8 * j + 4];
            acc[0] += fk * wa.x; acc[1] += fk * wa.y;
            acc[2] += fk * wa.z; acc[3] += fk * wa.w;
            acc[4] += fk * wb.x; acc[5] += fk * wb.y;
            acc[6] += fk * wb.z; acc[7] += fk * wb.w;
        }
        short8 h8;
#pragma unroll
        for (int cc = 0; cc < 8; ++cc) h8[cc] = (short)f2bf(acc[cc]);
        *(short8*)(xh + (size_t)n * 128 + 8 * j) = h8;
        r = rn;
    }
}

// ---------------------------------------------------------------------------
// CSR build: tiny scan -> bucket scatter -> local CSR
// ---------------------------------------------------------------------------
__global__ __launch_bounds__(256) void scanb_kernel(
    const int* __restrict__ bucket_counts, int* __restrict__ bucket_base,
    int* __restrict__ bucket_cursor, int* __restrict__ offsets)
{
    __shared__ int ws[4];
    int t = threadIdx.x;
    int c = (t < NBUCKETS) ? bucket_counts[t] : 0;
    int lane = t & 63, wid = t >> 6;
    int v = c;
#pragma unroll
    for (int off = 1; off < 64; off <<= 1) {
        int s = __shfl_up(v, off, 64);
        if (lane >= off) v += s;
    }
    if (lane == 63) ws[wid] = v;
    __syncthreads();
    if (t == 0) {
        int run = 0;
#pragma unroll
        for (int j = 0; j < 4; ++j) { int s = ws[j]; ws[j] = run; run += s; }
    }
    __syncthreads();
    int excl = ws[wid] + (v - c);
    if (t < NBUCKETS) {
        bucket_base[t] = excl;
        bucket_cursor[t] = excl;
    }
    if (t == 0) {
        bucket_base[NBUCKETS] = N_EDGES;
        offsets[N_NODES] = N_EDGES;
    }
}

__global__ __launch_bounds__(256) void bucket1_kernel(
    const int* __restrict__ src, const int* __restrict__ dst,
    int* __restrict__ bucket_cursor, uint2* __restrict__ pairs)
{
    __shared__ int hist[NBUCKETS];
    __shared__ int base[NBUCKETS];
    __shared__ int cur[NBUCKETS];
    int tid = threadIdx.x;
    for (int i = tid; i < NBUCKETS; i += 256) { hist[i] = 0; cur[i] = 0; }
    __syncthreads();
    int ebeg = blockIdx.x * CHUNK1;
    int eend = ebeg + CHUNK1;
    if (eend > N_EDGES) eend = N_EDGES;
    for (int e = ebeg + tid; e < eend; e += 256)
        atomicAdd(&hist[dst[e] >> 8], 1);
    __syncthreads();
    for (int i = tid; i < NBUCKETS; i += 256)
        if (hist[i] > 0) base[i] = atomicAdd(&bucket_cursor[i], hist[i]);
    __syncthreads();
    for (int e = ebeg + tid; e < eend; e += 256) {
        int d = dst[e];
        int b = d >> 8;
        int pos = base[b] + atomicAdd(&cur[b], 1);
        pairs[pos] = make_uint2((unsigned)src[e], (unsigned)d);
    }
}

__global__ __launch_bounds__(256) void bucket2_kernel(
    const uint2* __restrict__ pairs, const int* __restrict__ bucket_base,
    int* __restrict__ offsets, float* __restrict__ deg,
    int* __restrict__ src_sorted)
{
    __shared__ int cnt[256];
    __shared__ int noff[256];
    __shared__ int cur[256];
    __shared__ int ws[4];
    int b = blockIdx.x;
    int n0 = b << 8;
    int tid = threadIdx.x;
    int bb = bucket_base[b];
    int be = bucket_base[b + 1];
    cnt[tid] = 0;
    cur[tid] = 0;
    __syncthreads();
    for (int e = bb + tid; e < be; e += 256)
        atomicAdd(&cnt[pairs[e].y & 255], 1);
    __syncthreads();
    int c = cnt[tid];
    int lane = tid & 63, wid = tid >> 6;
    int v = c;
#pragma unroll
    for (int off = 1; off < 64; off <<= 1) {
        int s = __shfl_up(v, off, 64);
        if (lane >= off) v += s;
    }
    if (lane == 63) ws[wid] = v;
    __syncthreads();
    if (tid == 0) {
        int run = 0;
#pragma unroll
        for (int j = 0; j < 4; ++j) { int s = ws[j]; ws[j] = run; run += s; }
    }
    __syncthreads();
    int o = bb + ws[wid] + (v - c);
    noff[tid] = o;
    int n = n0 + tid;
    if (n < N_NODES) {
        offsets[n] = o;
        deg[n] = (float)(c > 0 ? c : 1);
    }
    __syncthreads();
    for (int e = bb + tid; e < be; e += 256) {
        uint2 p = pairs[e];
        int local = p.y & 255;
        int pos = noff[local] + atomicAdd(&cur[local], 1);
        src_sorted[pos] = (int)p.x;
    }
}

// ---------------------------------------------------------------------------
// Fused gather+GEMM: 512 thr / 8 waves, tile 128x128.
// Phase A: issue B(Wn_hi) async stage; each wave gather-means 16 of the
//   block's 128 dst nodes from xin (MLP=8) and ds-writes bf16 means into
//   the swizzled LDS A-tile. Phase B: MFMA mean*Wn_hi. Phase C: stage
//   xin rows + Ws_hi, MFMA. Epilogue: mode=1 relu -> xout plane (NOT
//   in-place: other blocks still gather xin); mode=2 fused head -> out.
// ---------------------------------------------------------------------------
#define BM 128
__global__ __launch_bounds__(512, 4) void gemm_fused(
    const unsigned short* __restrict__ xin, unsigned short* __restrict__ xout,
    const int* __restrict__ offsets, const int* __restrict__ src_sorted,
    const float* __restrict__ deg,
    const unsigned short* __restrict__ BT, const float* __restrict__ bias,
    int mode,
    const unsigned short* __restrict__ hwbh,
    const unsigned short* __restrict__ hwbl,
    const float* __restrict__ hb, float* __restrict__ out)
{
    __shared__ uint4 smem4[4096];           // 64 KB: As 32K | Bs 32K
    char* As = (char*)smem4;
    char* Bs = (char*)smem4 + 32768;
    __shared__ float bias_s[C];
    __shared__ unsigned short hwh_s[16 * 136];
    __shared__ unsigned short hwl_s[16 * 136];
    __shared__ float hb_s[OUT_DIM];

    int tid = threadIdx.x;
    int w = tid >> 6, l = tid & 63;
    int row0 = blockIdx.x * BM;
    if (tid < C) bias_s[tid] = bias[tid];
    if (mode == 2) {
        for (int i = tid; i < 16 * 136; i += 512) {
            hwh_s[i] = hwbh[i];
            hwl_s[i] = hwbl[i];
        }
        if (tid < OUT_DIM) hb_s[tid] = hb[tid];
    }

    int wm = w & 3;
    int wn = w >> 2;
    int quad = l >> 4;
    int mrow = l & 15;
    int h = l >> 4;     // 0..3: edge slot within a gather group
    int u = l & 15;     // 16 B unit (8 channels)

    // --- issue B stage for the Wn_hi chunk (seg 1) while we gather ---
#pragma unroll
    for (int i = 0; i < 4; ++i) {
        int off = i * 8192 + tid * 16;
        int n = off >> 8;
        int uu = ((off >> 4) & 15) ^ (n & 15);
        async16(Bs + off, (const char*)BT + (size_t)n * 512 + 256 + uu * 16);
    }

    // --- Phase A: gather-mean 16 nodes per wave into As (swizzled bf16) ---
    for (int i = 0; i < 16; ++i) {
        int rl = w * 16 + i;
        int node = row0 + rl;
        if (node > N_NODES - 1) node = N_NODES - 1;
        int beg = offsets[node];
        int end = offsets[node + 1];
        float acc[8];
#pragma unroll
        for (int j = 0; j < 8; ++j) acc[j] = 0.f;
        for (int e = beg; e < end; e += 32) {
            int idx[8], s[8];
#pragma unroll
            for (int t = 0; t < 8; ++t) {
                idx[t] = e + 4 * t + h;
                int cc = idx[t] < end ? idx[t] : beg;
                s[t] = src_sorted[cc];
            }
            uint4 v[8];
#pragma unroll
            for (int t = 0; t < 8; ++t)
                v[t] = *(const uint4*)(xin + (size_t)s[t] * 128 + u * 8);
#pragma unroll
            for (int t = 0; t < 8; ++t)
                if (idx[t] < end) add8(acc, v[t]);
        }
#pragma unroll
        for (int j = 0; j < 8; ++j) {
            acc[j] += __shfl_xor(acc[j], 16);
            acc[j] += __shfl_xor(acc[j], 32);
        }
        if (l < 16) {
            float inv = 1.0f / deg[node];
            short8 hv;
#pragma unroll
            for (int j = 0; j < 8; ++j)
                hv[j] = (short)f2bf(acc[j] * inv);
            int su = u ^ (rl & 15);
            *(short8*)(As + rl * 256 + su * 16) = hv;
        }
    }
    __syncthreads();

    f32x4 acc[2][4];
#pragma unroll
    for (int mt = 0; mt < 2; ++mt)
#pragma unroll
        for (int nt = 0; nt < 4; ++nt)
            acc[mt][nt] = (f32x4)(0.f);

    // --- Phase B: MFMA mean * Wn_hi ---
#pragma unroll
    for (int ks = 0; ks < 4; ++ks) {
        int cu = ks * 4 + quad;
        int swz = (cu ^ mrow) * 16;
        short8 a0 = *(const short8*)(As + (wm * 32 + mrow) * 256 + swz);
        short8 a1 = *(const short8*)(As + (wm * 32 + 16 + mrow) * 256 + swz);
        short8 b[4];
#pragma unroll
        for (int nt = 0; nt < 4; ++nt)
            b[nt] = *(const short8*)(Bs + (wn * 64 + nt * 16 + mrow) * 256 + swz);
#pragma unroll
        for (int nt = 0; nt < 4; ++nt) {
            acc[0][nt] = __builtin_amdgcn_mfma_f32_16x16x32_bf16(a0, b[nt], acc[0][nt], 0, 0, 0);
            acc[1][nt] = __builtin_amdgcn_mfma_f32_16x16x32_bf16(a1, b[nt], acc[1][nt], 0, 0, 0);
        }
    }
    __syncthreads();

    // --- Phase C: stage xin rows + Ws_hi (seg 0), MFMA ---
#pragma unroll
    for (int i = 0; i < 4; ++i) {
        int off = i * 8192 + tid * 16;
        int rl = off >> 8;
        int row = row0 + rl;
        if (row > N_NODES - 1) row = N_NODES - 1;
        int uu = ((off >> 4) & 15) ^ (rl & 15);
        async16(As + off, (const char*)xin + (size_t)row * 256 + uu * 16);
    }
#pragma unroll
    for (int i = 0; i < 4; ++i) {
        int off = i * 8192 + tid * 16;
        int n = off >> 8;
        int uu = ((off >> 4) & 15) ^ (n & 15);
        async16(Bs + off, (const char*)BT + (size_t)n * 512 + uu * 16);
    }
    __syncthreads();
#pragma unroll
    for (int ks = 0; ks < 4; ++ks) {
        int cu = ks * 4 + quad;
        int swz = (cu ^ mrow) * 16;
        short8 a0 = *(const short8*)(As + (wm * 32 + mrow) * 256 + swz);
        short8 a1 = *(const short8*)(As + (wm * 32 + 16 + mrow) * 256 + swz);
        short8 b[4];
#pragma unroll
        for (int nt = 0; nt < 4; ++nt)
            b[nt] = *(const short8*)(Bs + (wn * 64 + nt * 16 + mrow) * 256 + swz);
#pragma unroll
        for (int nt = 0; nt < 4; ++nt) {
            acc[0][nt] = __builtin_amdgcn_mfma_f32_16x16x32_bf16(a0, b[nt], acc[0][nt], 0, 0, 0);
            acc[1][nt] = __builtin_amdgcn_mfma_f32_16x16x32_bf16(a1, b[nt], acc[1][nt], 0, 0, 0);
        }
    }
    __syncthreads();

    // --- epilogue: bf16 tile in LDS, XOR-swizzled ---
    char* th = (char*)smem4;
    int relu = (mode == 1);
#pragma unroll
    for (int mt = 0; mt < 2; ++mt)
#pragma unroll
        for (int nt = 0; nt < 4; ++nt) {
            int col = wn * 64 + nt * 16 + mrow;
#pragma unroll
            for (int r = 0; r < 4; ++r) {
                int rl = wm * 32 + mt * 16 + quad * 4 + r;
                float v = acc[mt][nt][r] + bias_s[col];
                if (relu) v = fmaxf(v, 0.f);
                int su = (col >> 3) ^ (rl & 15);
                *(unsigned short*)(th + rl * 256 + su * 16 + (col & 7) * 2) =
                    f2bf(v);
            }
        }
    __syncthreads();

    if (mode == 1) {
#pragma unroll
        for (int i = 0; i < 4; ++i) {
            int off = i * 8192 + tid * 16;
            int rl = off >> 8;
            int su = (((off >> 4) & 15) ^ (rl & 15)) * 16;
            int row = row0 + rl;
            if (row < N_NODES)
                *(uint4*)((char*)xout + (size_t)row * 256 + (off & 255)) =
                    *(const uint4*)(th + rl * 256 + su);
        }
    } else {
        f32x4 hacc = (f32x4)(0.f);
        const unsigned short* Bp[2] = {hwh_s, hwl_s};
#pragma unroll
        for (int ps = 0; ps < 2; ++ps) {
#pragma unroll
            for (int ks = 0; ks < 4; ++ks) {
                int su = ((ks * 4 + quad) ^ mrow) * 16;
                short8 a = *(const short8*)(th + (w * 16 + mrow) * 256 + su);
                short8 b = *(const short8*)((const char*)Bp[ps] +
                                            mrow * 272 + ks * 64 + quad * 16);
                hacc = __builtin_amdgcn_mfma_f32_16x16x32_bf16(a, b, hacc, 0, 0, 0);
            }
        }
        float bb = hb_s[mrow];
#pragma unroll
        for (int r = 0; r < 4; ++r) {
            int grow = row0 + w * 16 + quad * 4 + r;
            if (grow < N_NODES)
                out[(size_t)grow * OUT_DIM + mrow] = hacc[r] + bb;
        }
    }
}

// ---------------------------------------------------------------------------
extern "C" void kernel_launch(void* const* d_in, const int* in_sizes, int n_in,
                              void* d_out, int out_size, void* d_ws, size_t ws_size,
                              hipStream_t stream)
{
    const float* feats0 = (const float*)d_in[0];
    const float* feats1 = (const float*)d_in[1];
    const float* enc_w0 = (const float*)d_in[2];
    const float* enc_b0 = (const float*)d_in[3];
    const float* enc_w1 = (const float*)d_in[4];
    const float* enc_b1 = (const float*)d_in[5];
    const float* w_self0 = (const float*)d_in[6];
    const float* w_neigh0 = (const float*)d_in[7];
    const float* b0 = (const float*)d_in[8];
    const float* w_self1 = (const float*)d_in[9];
    const float* w_neigh1 = (const float*)d_in[10];
    const float* b1 = (const float*)d_in[11];
    const float* head_w = (const float*)d_in[12];
    const float* head_b = (const float*)d_in[13];
    const int* node_row_idx = (const int*)d_in[14];
    const int* edge_index = (const int*)d_in[15];
    const int* e_src = edge_index;
    const int* e_dst = edge_index + N_EDGES;

    char* p = (char*)d_ws;
    unsigned short* xh = (unsigned short*)p;   p += (size_t)N_NODES * C * 2;
    unsigned short* xnew = (unsigned short*)p; p += (size_t)N_NODES * C * 2;
    unsigned short* BT0 = (unsigned short*)p;  p += (size_t)128 * 256 * 2;
    unsigned short* BT1 = (unsigned short*)p;  p += (size_t)128 * 256 * 2;
    unsigned short* hwbh = (unsigned short*)p; p += (size_t)16 * 136 * 2;
    unsigned short* hwbl = (unsigned short*)p; p += (size_t)16 * 136 * 2;
    float* deg = (float*)p;        p += (size_t)N_NODES * 4;
    int* offsets = (int*)p;        p += (size_t)(N_NODES + 8) * 4;
    int* bucket_counts = (int*)p;  p += (size_t)(NBUCKETS + 8) * 4;
    int* bucket_base = (int*)p;    p += (size_t)(NBUCKETS + 8) * 4;
    int* bucket_cursor = (int*)p;  p += (size_t)(NBUCKETS + 8) * 4;
    int* src_sorted = (int*)p;     p += (size_t)N_EDGES * 4;
    uint2* pairs = (uint2*)p;      p += (size_t)N_EDGES * 8;

    hipMemsetAsync(bucket_counts, 0, (size_t)(NBUCKETS + 8) * 4, stream);

    encode_hist_prep_kernel<<<ENC_BLOCKS + HIST_BLOCKS + PREP_BLOCKS, 256, 0,
                              stream>>>(
        feats0, feats1, enc_w0, enc_b0, enc_w1, enc_b1, node_row_idx, xh,
        e_dst, bucket_counts,
        w_self0, w_neigh0, w_self1, w_neigh1, head_w, BT0, BT1, hwbh, hwbl);

    scanb_kernel<<<1, 256, 0, stream>>>(bucket_counts, bucket_base,
                                        bucket_cursor, offsets);
    bucket1_kernel<<<NB1, 256, 0, stream>>>(e_src, e_dst, bucket_cursor, pairs);
    bucket2_kernel<<<NBUCKETS, 256, 0, stream>>>(pairs, bucket_base, offsets,
                                                 deg, src_sorted);

    // Layer 0: gather+GEMM fused, xh -> xnew
    gemm_fused<<<(N_NODES + BM - 1) / BM, 512, 0, stream>>>(
        xh, xnew, offsets, src_sorted, deg, BT0, b0, 1,
        hwbh, hwbl, head_b, (float*)d_out);

    // Layer 1: gather+GEMM+head fused, xnew -> out
    gemm_fused<<<(N_NODES + BM - 1) / BM, 512, 0, stream>>>(
        xnew, nullptr, offsets, src_sorted, deg, BT1, b1, 2,
        hwbh, hwbl, head_b, (float*)d_out);
}

// Round 15
// 227.413 us; speedup vs baseline: 1.0900x; 1.0900x over previous
//
#include <hip/hip_runtime.h>
#include <hip/hip_bf16.h>

#define N_NODES 50000
#define N_EDGES 800000
#define C 128
#define D_IN 32
#define T0 25000
#define OUT_DIM 16
#define NBUCKETS ((N_NODES + 255) / 256)      // 196, bucket = dst>>8
#define NB1 512
#define CHUNK1 ((N_EDGES + NB1 - 1) / NB1)    // 1563
#define ENC_BLOCKS 512
#define HIST_BLOCKS 256
#define PREP_ITEMS (2 * 128 * 256 + 2 * 16 * 128)
#define PREP_BLOCKS ((PREP_ITEMS + 255) / 256)

// Feature storage: single bf16 plane xh[N][128]; agg plane ah[N][128].
// GEMM K=256: segs {xh*Ws_hi, ah*Wn_hi}. Layer-1 fuses the head
// (hw split hi/lo, fp32-compensated).

typedef __attribute__((ext_vector_type(8))) short short8;
typedef __attribute__((ext_vector_type(4))) float f32x4;

__device__ __forceinline__ unsigned short f2bf(float f) {
    union { float f; unsigned int i; } u; u.f = f;
    unsigned int x = u.i;
    unsigned int r = x + 0x7fffu + ((x >> 16) & 1u);
    return (unsigned short)(r >> 16);
}
__device__ __forceinline__ float bf2f(unsigned short h) {
    union { unsigned int i; float f; } u; u.i = ((unsigned int)h) << 16;
    return u.f;
}
__device__ __forceinline__ float lo_f(unsigned int w) {
    union { unsigned int i; float f; } u; u.i = w << 16;
    return u.f;
}
__device__ __forceinline__ float hi_f(unsigned int w) {
    union { unsigned int i; float f; } u; u.i = w & 0xffff0000u;
    return u.f;
}
__device__ __forceinline__ void async16(void* lds, const void* g) {
    __builtin_amdgcn_global_load_lds(
        (const __attribute__((address_space(1))) void*)g,
        (__attribute__((address_space(3))) void*)lds, 16, 0, 0);
}
__device__ __forceinline__ void add8(float* a, uint4 v) {
    a[0] += lo_f(v.x); a[1] += hi_f(v.x);
    a[2] += lo_f(v.y); a[3] += hi_f(v.y);
    a[4] += lo_f(v.z); a[5] += hi_f(v.z);
    a[6] += lo_f(v.w); a[7] += hi_f(v.w);
}

// ---------------------------------------------------------------------------
// Mega-kernel: encode (blocks 0..511, row_idx software-pipelined) +
// bucket hist (512..767) + weight prep (768..).
// ---------------------------------------------------------------------------
__global__ __launch_bounds__(256) void encode_hist_prep_kernel(
    const float* __restrict__ feats0, const float* __restrict__ feats1,
    const float* __restrict__ w0, const float* __restrict__ b0,
    const float* __restrict__ w1, const float* __restrict__ b1,
    const int* __restrict__ row_idx, unsigned short* __restrict__ xh,
    const int* __restrict__ dst, int* __restrict__ bucket_counts,
    const float* __restrict__ ws0, const float* __restrict__ wn0,
    const float* __restrict__ ws1, const float* __restrict__ wn1,
    const float* __restrict__ hw,
    unsigned short* __restrict__ BT0, unsigned short* __restrict__ BT1,
    unsigned short* __restrict__ hwbh, unsigned short* __restrict__ hwbl)
{
    if (blockIdx.x >= ENC_BLOCKS + HIST_BLOCKS) {
        // ---- weight prep ----
        int idx = (blockIdx.x - ENC_BLOCKS - HIST_BLOCKS) * 256 + threadIdx.x;
        const int per_layer = 128 * 256;
        if (idx < 2 * per_layer) {
            int lyr = idx / per_layer;
            int rem = idx - lyr * per_layer;
            int n = rem >> 8;
            int k = rem & 255;
            int seg = k >> 7;     // 0:Ws_hi 1:Wn_hi
            int ch = k & 127;
            const float* W = (lyr == 0) ? (seg ? wn0 : ws0)
                                        : (seg ? wn1 : ws1);
            (lyr == 0 ? BT0 : BT1)[(size_t)n * 256 + k] =
                f2bf(W[ch * 128 + n]);
            return;
        }
        int jdx = idx - 2 * per_layer;
        if (jdx >= 2 * 16 * 128) return;
        int plane = jdx >> 11;
        int rem = jdx & 2047;
        int n = rem >> 7;
        int k = rem & 127;
        float v = hw[k * OUT_DIM + n];
        unsigned short hi = f2bf(v);
        (plane ? hwbl : hwbh)[n * 136 + k] = plane ? f2bf(v - bf2f(hi)) : hi;
        return;
    }
    if (blockIdx.x >= ENC_BLOCKS) {
        // ---- bucket histogram ----
        __shared__ int h[NBUCKETS];
        for (int i = threadIdx.x; i < NBUCKETS; i += 256) h[i] = 0;
        __syncthreads();
        int bid = blockIdx.x - ENC_BLOCKS;
        for (int e = bid * 256 + threadIdx.x; e < N_EDGES;
             e += HIST_BLOCKS * 256)
            atomicAdd(&h[dst[e] >> 8], 1);
        __syncthreads();
        for (int i = threadIdx.x; i < NBUCKETS; i += 256)
            if (h[i]) atomicAdd(&bucket_counts[i], h[i]);
        return;
    }

    // ---- encode (pipelined row_idx prefetch) ----
    __shared__ float sw0[D_IN * C];
    __shared__ float sw1[D_IN * C];
    __shared__ float sb0[C];
    __shared__ float sb1[C];
    for (int i = threadIdx.x; i < D_IN * C; i += blockDim.x) {
        sw0[i] = w0[i];
        sw1[i] = w1[i];
    }
    if (threadIdx.x < C) {
        sb0[threadIdx.x] = b0[threadIdx.x];
        sb1[threadIdx.x] = b1[threadIdx.x];
    }
    __syncthreads();

    const int STEP = ENC_BLOCKS * 16;
    int j = threadIdx.x & 15;
    int ln = threadIdx.x >> 4;
    int n = blockIdx.x * 16 + ln;
    int r = (n < N_NODES) ? row_idx[n] : 0;
    for (; n < N_NODES; n += STEP) {
        int nn = n + STEP;
        int rn = (nn < N_NODES) ? row_idx[nn] : 0;
        const float* f = (r < T0) ? (feats0 + (size_t)r * D_IN)
                                  : (feats1 + (size_t)(r - T0) * D_IN);
        const float* W = (r < T0) ? sw0 : sw1;
        const float* B = (r < T0) ? sb0 : sb1;
        float4 f4[8];
#pragma unroll
        for (int i = 0; i < 8; ++i) f4[i] = ((const float4*)f)[i];
        float acc[8];
#pragma unroll
        for (int cc = 0; cc < 8; ++cc) acc[cc] = B[8 * j + cc];
#pragma unroll
        for (int k = 0; k < D_IN; ++k) {
            float fk = ((const float*)f4)[k];
            float4 wa = *(const float4*)&W[k * C + 8 * j];
            float4 wb = *(const float4*)&W[k * C + 8 * j + 4];
            acc[0] += fk * wa.x; acc[1] += fk * wa.y;
            acc[2] += fk * wa.z; acc[3] += fk * wa.w;
            acc[4] += fk * wb.x; acc[5] += fk * wb.y;
            acc[6] += fk * wb.z; acc[7] += fk * wb.w;
        }
        short8 h8;
#pragma unroll
        for (int cc = 0; cc < 8; ++cc) h8[cc] = (short)f2bf(acc[cc]);
        *(short8*)(xh + (size_t)n * 128 + 8 * j) = h8;
        r = rn;
    }
}

// ---------------------------------------------------------------------------
// CSR build: tiny scan -> bucket scatter -> local CSR
// ---------------------------------------------------------------------------
__global__ __launch_bounds__(256) void scanb_kernel(
    const int* __restrict__ bucket_counts, int* __restrict__ bucket_base,
    int* __restrict__ bucket_cursor, int* __restrict__ offsets)
{
    __shared__ int ws[4];
    int t = threadIdx.x;
    int c = (t < NBUCKETS) ? bucket_counts[t] : 0;
    int lane = t & 63, wid = t >> 6;
    int v = c;
#pragma unroll
    for (int off = 1; off < 64; off <<= 1) {
        int s = __shfl_up(v, off, 64);
        if (lane >= off) v += s;
    }
    if (lane == 63) ws[wid] = v;
    __syncthreads();
    if (t == 0) {
        int run = 0;
#pragma unroll
        for (int j = 0; j < 4; ++j) { int s = ws[j]; ws[j] = run; run += s; }
    }
    __syncthreads();
    int excl = ws[wid] + (v - c);
    if (t < NBUCKETS) {
        bucket_base[t] = excl;
        bucket_cursor[t] = excl;
    }
    if (t == 0) {
        bucket_base[NBUCKETS] = N_EDGES;
        offsets[N_NODES] = N_EDGES;
    }
}

__global__ __launch_bounds__(256) void bucket1_kernel(
    const int* __restrict__ src, const int* __restrict__ dst,
    int* __restrict__ bucket_cursor, uint2* __restrict__ pairs)
{
    __shared__ int hist[NBUCKETS];
    __shared__ int base[NBUCKETS];
    __shared__ int cur[NBUCKETS];
    int tid = threadIdx.x;
    for (int i = tid; i < NBUCKETS; i += 256) { hist[i] = 0; cur[i] = 0; }
    __syncthreads();
    int ebeg = blockIdx.x * CHUNK1;
    int eend = ebeg + CHUNK1;
    if (eend > N_EDGES) eend = N_EDGES;
    for (int e = ebeg + tid; e < eend; e += 256)
        atomicAdd(&hist[dst[e] >> 8], 1);
    __syncthreads();
    for (int i = tid; i < NBUCKETS; i += 256)
        if (hist[i] > 0) base[i] = atomicAdd(&bucket_cursor[i], hist[i]);
    __syncthreads();
    for (int e = ebeg + tid; e < eend; e += 256) {
        int d = dst[e];
        int b = d >> 8;
        int pos = base[b] + atomicAdd(&cur[b], 1);
        pairs[pos] = make_uint2((unsigned)src[e], (unsigned)d);
    }
}

__global__ __launch_bounds__(256) void bucket2_kernel(
    const uint2* __restrict__ pairs, const int* __restrict__ bucket_base,
    int* __restrict__ offsets, float* __restrict__ deg,
    int* __restrict__ src_sorted)
{
    __shared__ int cnt[256];
    __shared__ int noff[256];
    __shared__ int cur[256];
    __shared__ int ws[4];
    int b = blockIdx.x;
    int n0 = b << 8;
    int tid = threadIdx.x;
    int bb = bucket_base[b];
    int be = bucket_base[b + 1];
    cnt[tid] = 0;
    cur[tid] = 0;
    __syncthreads();
    for (int e = bb + tid; e < be; e += 256)
        atomicAdd(&cnt[pairs[e].y & 255], 1);
    __syncthreads();
    int c = cnt[tid];
    int lane = tid & 63, wid = tid >> 6;
    int v = c;
#pragma unroll
    for (int off = 1; off < 64; off <<= 1) {
        int s = __shfl_up(v, off, 64);
        if (lane >= off) v += s;
    }
    if (lane == 63) ws[wid] = v;
    __syncthreads();
    if (tid == 0) {
        int run = 0;
#pragma unroll
        for (int j = 0; j < 4; ++j) { int s = ws[j]; ws[j] = run; run += s; }
    }
    __syncthreads();
    int o = bb + ws[wid] + (v - c);
    noff[tid] = o;
    int n = n0 + tid;
    if (n < N_NODES) {
        offsets[n] = o;
        deg[n] = (float)(c > 0 ? c : 1);
    }
    __syncthreads();
    for (int e = bb + tid; e < be; e += 256) {
        uint2 p = pairs[e];
        int local = p.y & 255;
        int pos = noff[local] + atomicAdd(&cur[local], 1);
        src_sorted[pos] = (int)p.x;
    }
}

// ---------------------------------------------------------------------------
// Aggregate: one wave per dst node. lane = h*16 + u; one wave-load covers
// FOUR edges; 32 edges / 8 independent gathers per iteration (MLP=8).
// ---------------------------------------------------------------------------
__global__ __launch_bounds__(256, 8) void aggregate_kernel(
    const unsigned short* __restrict__ xh, const int* __restrict__ offsets,
    const int* __restrict__ src_sorted, const float* __restrict__ deg,
    unsigned short* __restrict__ ah)
{
    int wave = (blockIdx.x * blockDim.x + threadIdx.x) >> 6;
    int lane = threadIdx.x & 63;
    if (wave >= N_NODES) return;
    int h = lane >> 4;
    int u = lane & 15;
    int beg = offsets[wave];
    int end = offsets[wave + 1];
    float acc[8];
#pragma unroll
    for (int j = 0; j < 8; ++j) acc[j] = 0.f;

    for (int e = beg; e < end; e += 32) {
        int idx[8], s[8];
#pragma unroll
        for (int t = 0; t < 8; ++t) {
            idx[t] = e + 4 * t + h;
            int cc = idx[t] < end ? idx[t] : beg;
            s[t] = src_sorted[cc];
        }
        uint4 v[8];
#pragma unroll
        for (int t = 0; t < 8; ++t)
            v[t] = *(const uint4*)(xh + (size_t)s[t] * 128 + u * 8);
#pragma unroll
        for (int t = 0; t < 8; ++t)
            if (idx[t] < end) add8(acc, v[t]);
    }

#pragma unroll
    for (int j = 0; j < 8; ++j) {
        acc[j] += __shfl_xor(acc[j], 16);
        acc[j] += __shfl_xor(acc[j], 32);
    }
    if (lane < 16) {
        float inv = 1.0f / deg[wave];
        short8 hv;
#pragma unroll
        for (int j = 0; j < 8; ++j)
            hv[j] = (short)f2bf(acc[j] * inv);
        *(short8*)(ah + (size_t)wave * 128 + u * 8) = hv;
    }
}

// ---------------------------------------------------------------------------
// Layer GEMM: 512 thr / 8 waves, tile 128x128, K=256 in 2 chunks of 128:
// {xh*Ws_hi, ah*Wn_hi}. BT row = 256 slots (512 B).
// mode=1: relu, write xh plane. mode=2: fused head -> out[N][16].
// ---------------------------------------------------------------------------
#define BM 128
__global__ __launch_bounds__(512) void gemm_mfma(
    unsigned short* __restrict__ xh, const unsigned short* __restrict__ ah,
    const unsigned short* __restrict__ BT, const float* __restrict__ bias,
    int mode,
    const unsigned short* __restrict__ hwbh,
    const unsigned short* __restrict__ hwbl,
    const float* __restrict__ hb, float* __restrict__ out)
{
    __shared__ uint4 smem4[4096];           // 64 KB: As 32K | Bs 32K / th
    char* As = (char*)smem4;
    char* Bs = (char*)smem4 + 32768;
    __shared__ float bias_s[C];
    __shared__ unsigned short hwh_s[16 * 136];
    __shared__ unsigned short hwl_s[16 * 136];
    __shared__ float hb_s[OUT_DIM];

    int tid = threadIdx.x;
    int w = tid >> 6, l = tid & 63;
    int row0 = blockIdx.x * BM;
    if (tid < C) bias_s[tid] = bias[tid];
    if (mode == 2) {
        for (int i = tid; i < 16 * 136; i += 512) {
            hwh_s[i] = hwbh[i];
            hwl_s[i] = hwbl[i];
        }
        if (tid < OUT_DIM) hb_s[tid] = hb[tid];
    }

    f32x4 acc[2][4];
#pragma unroll
    for (int mt = 0; mt < 2; ++mt)
#pragma unroll
        for (int nt = 0; nt < 4; ++nt)
            acc[mt][nt] = (f32x4)(0.f);

    int wm = w & 3;
    int wn = w >> 2;
    int quad = l >> 4;
    int mrow = l & 15;

    for (int c = 0; c < 2; ++c) {
        const char* abase = (const char*)(c == 0 ? xh : ah);
#pragma unroll
        for (int i = 0; i < 4; ++i) {
            int off = i * 8192 + tid * 16;
            int rl = off >> 8;
            int row = row0 + rl;
            if (row > N_NODES - 1) row = N_NODES - 1;
            int u = ((off >> 4) & 15) ^ (rl & 15);
            async16(As + off, abase + (size_t)row * 256 + u * 16);
        }
#pragma unroll
        for (int i = 0; i < 4; ++i) {
            int off = i * 8192 + tid * 16;
            int n = off >> 8;
            int u = ((off >> 4) & 15) ^ (n & 15);
            async16(Bs + off, (const char*)BT + (size_t)n * 512 + c * 256 + u * 16);
        }
        __syncthreads();
#pragma unroll
        for (int ks = 0; ks < 4; ++ks) {
            int cu = ks * 4 + quad;
            int swz = (cu ^ mrow) * 16;
            short8 a0 = *(const short8*)(As + (wm * 32 + mrow) * 256 + swz);
            short8 a1 = *(const short8*)(As + (wm * 32 + 16 + mrow) * 256 + swz);
            short8 b[4];
#pragma unroll
            for (int nt = 0; nt < 4; ++nt)
                b[nt] = *(const short8*)(Bs + (wn * 64 + nt * 16 + mrow) * 256 + swz);
#pragma unroll
            for (int nt = 0; nt < 4; ++nt) {
                acc[0][nt] = __builtin_amdgcn_mfma_f32_16x16x32_bf16(a0, b[nt], acc[0][nt], 0, 0, 0);
                acc[1][nt] = __builtin_amdgcn_mfma_f32_16x16x32_bf16(a1, b[nt], acc[1][nt], 0, 0, 0);
            }
        }
        __syncthreads();
    }

    // epilogue: bf16 tile in LDS, XOR-swizzled (unit' = unit ^ (rl&15))
    char* th = (char*)smem4;            // 32 KB: 128 rows x 256 B
    int relu = (mode == 1);
#pragma unroll
    for (int mt = 0; mt < 2; ++mt)
#pragma unroll
        for (int nt = 0; nt < 4; ++nt) {
            int col = wn * 64 + nt * 16 + mrow;
#pragma unroll
            for (int r = 0; r < 4; ++r) {
                int rl = wm * 32 + mt * 16 + quad * 4 + r;
                float v = acc[mt][nt][r] + bias_s[col];
                if (relu) v = fmaxf(v, 0.f);
                int su = (col >> 3) ^ (rl & 15);
                *(unsigned short*)(th + rl * 256 + su * 16 + (col & 7) * 2) =
                    f2bf(v);
            }
        }
    __syncthreads();

    if (mode == 1) {
        // unswizzling copy-out to xh
#pragma unroll
        for (int i = 0; i < 4; ++i) {
            int off = i * 8192 + tid * 16;
            int rl = off >> 8;
            int su = (((off >> 4) & 15) ^ (rl & 15)) * 16;
            int row = row0 + rl;
            if (row < N_NODES)
                *(uint4*)((char*)xh + (size_t)row * 256 + (off & 255)) =
                    *(const uint4*)(th + rl * 256 + su);
        }
    } else {
        // fused head: out_tile = th @ (hwh + hwl) + hb
        f32x4 hacc = (f32x4)(0.f);
        const unsigned short* Bp[2] = {hwh_s, hwl_s};
#pragma unroll
        for (int ps = 0; ps < 2; ++ps) {
#pragma unroll
            for (int ks = 0; ks < 4; ++ks) {
                int su = ((ks * 4 + quad) ^ mrow) * 16;
                short8 a = *(const short8*)(th + (w * 16 + mrow) * 256 + su);
                short8 b = *(const short8*)((const char*)Bp[ps] +
                                            mrow * 272 + ks * 64 + quad * 16);
                hacc = __builtin_amdgcn_mfma_f32_16x16x32_bf16(a, b, hacc, 0, 0, 0);
            }
        }
        float bb = hb_s[mrow];
#pragma unroll
        for (int r = 0; r < 4; ++r) {
            int grow = row0 + w * 16 + quad * 4 + r;
            if (grow < N_NODES)
                out[(size_t)grow * OUT_DIM + mrow] = hacc[r] + bb;
        }
    }
}

// ---------------------------------------------------------------------------
extern "C" void kernel_launch(void* const* d_in, const int* in_sizes, int n_in,
                              void* d_out, int out_size, void* d_ws, size_t ws_size,
                              hipStream_t stream)
{
    const float* feats0 = (const float*)d_in[0];
    const float* feats1 = (const float*)d_in[1];
    const float* enc_w0 = (const float*)d_in[2];
    const float* enc_b0 = (const float*)d_in[3];
    const float* enc_w1 = (const float*)d_in[4];
    const float* enc_b1 = (const float*)d_in[5];
    const float* w_self0 = (const float*)d_in[6];
    const float* w_neigh0 = (const float*)d_in[7];
    const float* b0 = (const float*)d_in[8];
    const float* w_self1 = (const float*)d_in[9];
    const float* w_neigh1 = (const float*)d_in[10];
    const float* b1 = (const float*)d_in[11];
    const float* head_w = (const float*)d_in[12];
    const float* head_b = (const float*)d_in[13];
    const int* node_row_idx = (const int*)d_in[14];
    const int* edge_index = (const int*)d_in[15];
    const int* e_src = edge_index;
    const int* e_dst = edge_index + N_EDGES;

    char* p = (char*)d_ws;
    unsigned short* xh = (unsigned short*)p;  p += (size_t)N_NODES * C * 2;
    unsigned short* ah = (unsigned short*)p;  p += (size_t)N_NODES * C * 2;
    unsigned short* BT0 = (unsigned short*)p; p += (size_t)128 * 256 * 2;
    unsigned short* BT1 = (unsigned short*)p; p += (size_t)128 * 256 * 2;
    unsigned short* hwbh = (unsigned short*)p; p += (size_t)16 * 136 * 2;
    unsigned short* hwbl = (unsigned short*)p; p += (size_t)16 * 136 * 2;
    float* deg = (float*)p;        p += (size_t)N_NODES * 4;
    int* offsets = (int*)p;        p += (size_t)(N_NODES + 8) * 4;
    int* bucket_counts = (int*)p;  p += (size_t)(NBUCKETS + 8) * 4;
    int* bucket_base = (int*)p;    p += (size_t)(NBUCKETS + 8) * 4;
    int* bucket_cursor = (int*)p;  p += (size_t)(NBUCKETS + 8) * 4;
    int* src_sorted = (int*)p;     p += (size_t)N_EDGES * 4;
    // pairs aliases ah (ah unwritten until aggregate, which runs after
    // bucket2 on the same stream): 800K * 8 B = 6.4 MB <= 12.8 MB
    uint2* pairs = (uint2*)ah;

    hipMemsetAsync(bucket_counts, 0, (size_t)(NBUCKETS + 8) * 4, stream);

    encode_hist_prep_kernel<<<ENC_BLOCKS + HIST_BLOCKS + PREP_BLOCKS, 256, 0,
                              stream>>>(
        feats0, feats1, enc_w0, enc_b0, enc_w1, enc_b1, node_row_idx, xh,
        e_dst, bucket_counts,
        w_self0, w_neigh0, w_self1, w_neigh1, head_w, BT0, BT1, hwbh, hwbl);

    scanb_kernel<<<1, 256, 0, stream>>>(bucket_counts, bucket_base,
                                        bucket_cursor, offsets);
    bucket1_kernel<<<NB1, 256, 0, stream>>>(e_src, e_dst, bucket_cursor, pairs);
    bucket2_kernel<<<NBUCKETS, 256, 0, stream>>>(pairs, bucket_base, offsets,
                                                 deg, src_sorted);

    // Layer 0
    aggregate_kernel<<<(N_NODES * 64 + 255) / 256, 256, 0, stream>>>(
        xh, offsets, src_sorted, deg, ah);
    gemm_mfma<<<(N_NODES + BM - 1) / BM, 512, 0, stream>>>(
        xh, ah, BT0, b0, 1, hwbh, hwbl, head_b, (float*)d_out);

    // Layer 1 (fused head)
    aggregate_kernel<<<(N_NODES * 64 + 255) / 256, 256, 0, stream>>>(
        xh, offsets, src_sorted, deg, ah);
    gemm_mfma<<<(N_NODES + BM - 1) / BM, 512, 0, stream>>>(
        xh, ah, BT1, b1, 2, hwbh, hwbl, head_b, (float*)d_out);
}